// Round 4
// baseline (111.098 us; speedup 1.0000x reference)
//
#include <hip/hip_runtime.h>

// B=8, L=512, D=512, H=8. Q/K GEMMs: M=4096, N=4096, K=512 (bf16 MFMA, 256^2 8-phase).
// V path (all f32): P' = softmax + 63.875; c = sum_l P'; Y = sum_l P'*Xv;
//   out = Y @ Wv (split-K) + c*bv.

using bf16x8 = __attribute__((ext_vector_type(8))) short;
using f32x4  = __attribute__((ext_vector_type(4))) float;

__device__ __forceinline__ unsigned short f2bf(float f) {
    union { float f; unsigned int u; } c; c.f = f;
    unsigned int u = c.u;
    u += 0x7FFFu + ((u >> 16) & 1u);   // RTNE
    return (unsigned short)(u >> 16);
}
__device__ __forceinline__ float bflo(unsigned int u) {
    union { unsigned int u; float f; } c; c.u = u << 16; return c.f;
}
__device__ __forceinline__ float bfhi(unsigned int u) {
    union { unsigned int u; float f; } c; c.u = u & 0xFFFF0000u; return c.f;
}

#define GLOAD16(gp, lp) __builtin_amdgcn_global_load_lds( \
    (const __attribute__((address_space(1))) unsigned int*)(gp), \
    (__attribute__((address_space(3))) unsigned int*)(lp), 16, 0, 0)

// ---------------- kernel 1: convert Xq, Xk (f32 -> bf16) ----------------------------
__global__ void convert_x(const float* __restrict__ x0, const float* __restrict__ x1,
                          unsigned short* __restrict__ o0, unsigned short* __restrict__ o1,
                          int n)
{
    const float* src = (blockIdx.z == 0) ? x0 : x1;
    unsigned short* dst = (blockIdx.z == 0) ? o0 : o1;
    int i = (blockIdx.x * blockDim.x + threadIdx.x) * 4;
    if (i < n) {
        float4 v = *(const float4*)(src + i);
        ushort4 o;
        o.x = f2bf(v.x); o.y = f2bf(v.y); o.z = f2bf(v.z); o.w = f2bf(v.w);
        *(ushort4*)(dst + i) = o;
    }
}

// ---------------- kernel 2: transpose-convert Wq, Wk (512x4096 f32 -> 4096x512 bf16) -
__global__ void transpose_w(const float* __restrict__ w0, const float* __restrict__ w1,
                            unsigned short* __restrict__ t0, unsigned short* __restrict__ t1)
{
    const float* W = (blockIdx.z == 0) ? w0 : w1;
    unsigned short* T = (blockIdx.z == 0) ? t0 : t1;
    __shared__ float tile[32][33];
    const int n0 = blockIdx.x * 32, k0 = blockIdx.y * 32;
    const int tx = threadIdx.x, ty = threadIdx.y;   // (32, 8)
    #pragma unroll
    for (int j = 0; j < 32; j += 8)
        tile[ty + j][tx] = W[(size_t)(k0 + ty + j) * 4096 + n0 + tx];
    __syncthreads();
    #pragma unroll
    for (int j = 0; j < 32; j += 8)
        T[(size_t)(n0 + ty + j) * 512 + k0 + tx] = f2bf(tile[tx][ty + j]);
}

// ---------------- kernel 3: 256^2 8-phase bf16 GEMM C = A @ Bt^T + bias --------------
// 512 thr (8 waves, 2M x 4N), BK=64, LDS 128 KiB (2 buf x (A 256x64 + B 256x64)).
// Counted vmcnt(4) at phases 3/7 only; raw s_barrier; setprio around MFMA clusters.
__global__ __launch_bounds__(512) void gemm_bt256(
    const unsigned short* __restrict__ a0, const unsigned short* __restrict__ a1,
    const unsigned short* __restrict__ w0, const unsigned short* __restrict__ w1,
    const float* __restrict__ b0, const float* __restrict__ b1,
    unsigned short* __restrict__ c0, unsigned short* __restrict__ c1)
{
    const unsigned short* A;  const unsigned short* Bt; const float* bias; unsigned short* C;
    if (blockIdx.z == 0) { A = a0; Bt = w0; bias = b0; C = c0; }
    else                 { A = a1; Bt = w1; bias = b1; C = c1; }

    __shared__ __align__(16) unsigned short As[2][16384];   // [buf][256 rows x 64 k]
    __shared__ __align__(16) unsigned short Bs[2][16384];

    const int tid  = threadIdx.x;
    const int lane = tid & 63;
    const int wid  = tid >> 6;          // 0..7
    const int wr   = wid >> 2;          // 0..1  (M half)
    const int wn   = wid & 3;           // 0..3  (N quarter)
    const int row0 = blockIdx.y * 256;
    const int n0   = blockIdx.x * 256;
    const int sgran = (lane & 7) ^ (lane >> 3);   // inverse-swizzled source granule

    // stage one half-tile (128 rows) of K-tile `tile` into OPs[buf]: 2 issues
#define STAGE(OPs, OPg, gbase, buf, half, tile)                                   \
    {                                                                             \
        const int rb0 = (half) * 128 + wid * 8;                                   \
        GLOAD16((OPg) + (size_t)((gbase) + rb0 + (lane >> 3)) * 512               \
                       + (tile) * 64 + sgran * 8, &OPs[buf][rb0 * 64]);           \
        const int rb1 = rb0 + 64;                                                 \
        GLOAD16((OPg) + (size_t)((gbase) + rb1 + (lane >> 3)) * 512               \
                       + (tile) * 64 + sgran * 8, &OPs[buf][rb1 * 64]);           \
    }

#define LD_A(c, m, s) (*(const bf16x8*)((const char*)&As[c][0]                    \
        + (wr * 128 + (m) * 16 + (lane & 15)) * 128                               \
        + ((((s) * 4 + (lane >> 4)) ^ ((wr * 128 + (m) * 16 + (lane & 15)) & 7)) << 4)))
#define LD_B(c, n, s) (*(const bf16x8*)((const char*)&Bs[c][0]                    \
        + (wn * 64 + (n) * 16 + (lane & 15)) * 128                                \
        + ((((s) * 4 + (lane >> 4)) ^ ((wn * 64 + (n) * 16 + (lane & 15)) & 7)) << 4)))

#define BAR() __builtin_amdgcn_s_barrier()
#define VMC4() asm volatile("s_waitcnt vmcnt(4)" ::: "memory")
#define VMC0() asm volatile("s_waitcnt vmcnt(0)" ::: "memory")

    f32x4 acc[8][4];
    #pragma unroll
    for (int m = 0; m < 8; ++m)
        #pragma unroll
        for (int n = 0; n < 4; ++n)
            acc[m][n] = (f32x4){0.f, 0.f, 0.f, 0.f};

    bf16x8 bfr[4][2];
    bf16x8 fa0, fa1, fa2, fa3;

#define LDA_Q(c, q) { fa0 = LD_A(c, 2*(q), 0); fa1 = LD_A(c, 2*(q), 1);           \
                      fa2 = LD_A(c, 2*(q)+1, 0); fa3 = LD_A(c, 2*(q)+1, 1); }
#define LDB_ALL(c) { _Pragma("unroll") for (int n = 0; n < 4; ++n) {              \
                       bfr[n][0] = LD_B(c, n, 0); bfr[n][1] = LD_B(c, n, 1); } }
#define MFMA_Q(q) { __builtin_amdgcn_s_setprio(1);                                \
    _Pragma("unroll") for (int n = 0; n < 4; ++n) {                               \
      acc[2*(q)][n]   = __builtin_amdgcn_mfma_f32_16x16x32_bf16(fa0, bfr[n][0], acc[2*(q)][n],   0,0,0); \
      acc[2*(q)][n]   = __builtin_amdgcn_mfma_f32_16x16x32_bf16(fa1, bfr[n][1], acc[2*(q)][n],   0,0,0); \
      acc[2*(q)+1][n] = __builtin_amdgcn_mfma_f32_16x16x32_bf16(fa2, bfr[n][0], acc[2*(q)+1][n], 0,0,0); \
      acc[2*(q)+1][n] = __builtin_amdgcn_mfma_f32_16x16x32_bf16(fa3, bfr[n][1], acc[2*(q)+1][n], 0,0,0); } \
    __builtin_amdgcn_s_setprio(0); }

    // prologue: buf0.B(t0), buf0.A(t0), buf1.B(t1)  -> 12 issues
    STAGE(Bs, Bt, n0, 0, 0, 0); STAGE(Bs, Bt, n0, 0, 1, 0);
    STAGE(As, A,  row0, 0, 0, 0); STAGE(As, A,  row0, 0, 1, 0);
    STAGE(Bs, Bt, n0, 1, 0, 1); STAGE(Bs, Bt, n0, 1, 1, 1);
    VMC4();          // tile0 (first 8 issues) resident
    BAR();

    for (int i = 0; i < 4; ++i) {
        const int t1 = 2 * i + 1, t2 = 2 * i + 2, t3 = 2 * i + 3;
        const bool s2 = (t2 < 8), s3 = (t3 < 8);

        // p0: compute buf0 q0 (+B-frags), stage buf1.A h0 (tile t1)
        LDA_Q(0, 0); LDB_ALL(0);
        STAGE(As, A, row0, 1, 0, t1);
        BAR(); MFMA_Q(0); BAR();
        // p1
        LDA_Q(0, 1);
        STAGE(As, A, row0, 1, 1, t1);
        BAR(); MFMA_Q(1); BAR();
        // p2
        LDA_Q(0, 2);
        if (s2) STAGE(Bs, Bt, n0, 0, 0, t2);
        BAR(); MFMA_Q(2); BAR();
        // p3 (+vmcnt)
        LDA_Q(0, 3);
        if (s2) STAGE(Bs, Bt, n0, 0, 1, t2);
        BAR(); MFMA_Q(3);
        if (i < 3) { VMC4(); } else { VMC0(); }
        BAR();
        // p4: compute buf1 q0 (+B-frags), stage buf0.A h0 (tile t2)
        LDA_Q(1, 0); LDB_ALL(1);
        if (s2) STAGE(As, A, row0, 0, 0, t2);
        BAR(); MFMA_Q(0); BAR();
        // p5
        LDA_Q(1, 1);
        if (s2) STAGE(As, A, row0, 0, 1, t2);
        BAR(); MFMA_Q(1); BAR();
        // p6
        LDA_Q(1, 2);
        if (s3) STAGE(Bs, Bt, n0, 1, 0, t3);
        BAR(); MFMA_Q(2); BAR();
        // p7 (+vmcnt)
        LDA_Q(1, 3);
        if (s3) STAGE(Bs, Bt, n0, 1, 1, t3);
        BAR(); MFMA_Q(3);
        if (i < 3) { VMC4(); }
        BAR();
    }

    // epilogue: C/D layout col = lane&15, row = (lane>>4)*4 + r
    #pragma unroll
    for (int n = 0; n < 4; ++n) {
        const int cg = n0 + wn * 64 + n * 16 + (lane & 15);
        const float bb = bias[cg];
        #pragma unroll
        for (int m = 0; m < 8; ++m) {
            const int r0 = row0 + wr * 128 + m * 16 + (lane >> 4) * 4;
            #pragma unroll
            for (int r = 0; r < 4; ++r)
                C[(size_t)(r0 + r) * 4096 + cg] = f2bf(acc[m][n][r] + bb);
        }
    }
#undef STAGE
#undef LD_A
#undef LD_B
}

// ---------------- kernel 4: scores + softmax -> P' = p + 63.875 ---------------------
__global__ __launch_bounds__(64) void scores(const unsigned short* __restrict__ Q,
                                             const unsigned short* __restrict__ K,
                                             float* __restrict__ P)
{
    __shared__ __align__(16) unsigned short qs[8 * 520];
    __shared__ __align__(16) unsigned short ks[8 * 520];
    const int r = blockIdx.x;        // b*512 + l
    const int lane = threadIdx.x;    // 64
    const unsigned short* qrow = Q + (size_t)r * 4096;
    const unsigned short* krow = K + (size_t)r * 4096;
    #pragma unroll
    for (int m = 0; m < 8; ++m) {
        *(uint4*)(&qs[m * 520 + lane * 8]) = *(const uint4*)(qrow + m * 512 + lane * 8);
        *(uint4*)(&ks[m * 520 + lane * 8]) = *(const uint4*)(krow + m * 512 + lane * 8);
    }
    __syncthreads();

    const int h = lane >> 3, g = lane & 7;
    const unsigned short* qh = &qs[h * 520];
    const unsigned short* kg = &ks[g * 520];
    float dot = 0.f;
    #pragma unroll 4
    for (int m = 0; m < 64; ++m) {
        uint4 qa = *(const uint4*)(qh + m * 8);
        uint4 ka = *(const uint4*)(kg + m * 8);
        dot += bflo(qa.x) * bflo(ka.x) + bfhi(qa.x) * bfhi(ka.x);
        dot += bflo(qa.y) * bflo(ka.y) + bfhi(qa.y) * bfhi(ka.y);
        dot += bflo(qa.z) * bflo(ka.z) + bfhi(qa.z) * bfhi(ka.z);
        dot += bflo(qa.w) * bflo(ka.w) + bfhi(qa.w) * bfhi(ka.w);
    }
    float s = dot * 0.04419417382415922f;   // 1/sqrt(512)
    float mx = s;
    mx = fmaxf(mx, __shfl_xor(mx, 1));
    mx = fmaxf(mx, __shfl_xor(mx, 2));
    mx = fmaxf(mx, __shfl_xor(mx, 4));
    float e = __expf(s - mx);
    float sm = e;
    sm += __shfl_xor(sm, 1);
    sm += __shfl_xor(sm, 2);
    sm += __shfl_xor(sm, 4);
    P[(size_t)r * 64 + lane] = e / sm + 63.875f;   // fold uniform part into P
}

// ---------------- kernel 5: c[b,hg] = sum_l P' ---------------------------------------
__global__ __launch_bounds__(256) void pbkern(const float* __restrict__ P,
                                              float* __restrict__ c)
{
    __shared__ float red[256];
    const int b = blockIdx.x, tid = threadIdx.x;
    const int hg = tid & 63, q = tid >> 6;
    float s = 0.f;
    for (int l = 0; l < 128; ++l) s += P[((size_t)b * 512 + q * 128 + l) * 64 + hg];
    red[tid] = s;
    __syncthreads();
    if (q == 0) c[b * 64 + hg] = red[hg] + red[64 + hg] + red[128 + hg] + red[192 + hg];
}

// ---------------- kernel 6: ypart[lc,b,hg,d] = sum_{l in chunk} P' * Xv --------------
__global__ __launch_bounds__(256) void ykern(const float* __restrict__ P,
                                             const float* __restrict__ Xv,
                                             float* __restrict__ ypart)
{
    __shared__ float Pl[128 * 64];
    __shared__ float Xl[128 * 64];
    const int b = blockIdx.x, dt = blockIdx.y, lc = blockIdx.z;
    const int tid = threadIdx.x;
    const int tm = tid & 15, te = tid >> 4;

    const float* Pg = P + ((size_t)b * 512 + lc * 128) * 64;
    #pragma unroll
    for (int i = 0; i < 8; ++i)
        *(float4*)&Pl[(i * 256 + tid) * 4] = *(const float4*)(Pg + (size_t)(i * 256 + tid) * 4);
    const float* Xg = Xv + ((size_t)b * 512 + lc * 128) * 512 + dt * 64;
    #pragma unroll
    for (int i = 0; i < 8; ++i) {
        int flat = i * 256 + tid;            // 2048 float4 = 128 rows x 16
        int r = flat >> 4, q = flat & 15;
        *(float4*)&Xl[r * 64 + q * 4] = *(const float4*)(Xg + (size_t)r * 512 + q * 4);
    }
    __syncthreads();

    float4 acc[4];
    #pragma unroll
    for (int i = 0; i < 4; ++i) acc[i] = make_float4(0.f, 0.f, 0.f, 0.f);

    for (int l = 0; l < 128; ++l) {
        float4 pv = *(const float4*)&Pl[l * 64 + tm * 4];
        float4 xv = *(const float4*)&Xl[l * 64 + te * 4];
        acc[0].x += pv.x * xv.x; acc[0].y += pv.x * xv.y; acc[0].z += pv.x * xv.z; acc[0].w += pv.x * xv.w;
        acc[1].x += pv.y * xv.x; acc[1].y += pv.y * xv.y; acc[1].z += pv.y * xv.z; acc[1].w += pv.y * xv.w;
        acc[2].x += pv.z * xv.x; acc[2].y += pv.z * xv.y; acc[2].z += pv.z * xv.z; acc[2].w += pv.z * xv.w;
        acc[3].x += pv.w * xv.x; acc[3].y += pv.w * xv.y; acc[3].z += pv.w * xv.z; acc[3].w += pv.w * xv.w;
    }
    #pragma unroll
    for (int i = 0; i < 4; ++i)
        *(float4*)&ypart[(((size_t)lc * 8 + b) * 64 + tm * 4 + i) * 512 + dt * 64 + te * 4] = acc[i];
}

// ---------------- kernel 7: Y = sum_lc ypart ------------------------------------------
__global__ void yreduce(const float* __restrict__ ypart, float* __restrict__ Y)
{
    int fi = (blockIdx.x * 256 + threadIdx.x) * 4;   // 262144 floats
    float4 s = *(const float4*)(ypart + fi);
    #pragma unroll
    for (int lc = 1; lc < 4; ++lc) {
        float4 t = *(const float4*)(ypart + (size_t)lc * 262144 + fi);
        s.x += t.x; s.y += t.y; s.z += t.z; s.w += t.w;
    }
    *(float4*)(Y + fi) = s;
}

// ---------------- kernel 8: split-K vgemm: partial[kc,bh,e] --------------------------
__global__ __launch_bounds__(256) void vgemm(const float* __restrict__ Y,
                                             const float* __restrict__ Wv,
                                             float* __restrict__ partial)
{
    __shared__ float Al[64 * 64];   // [bh][d], granule-XOR swizzled
    __shared__ float Bl[64 * 64];   // [kk][e] linear
    const int et = blockIdx.x, kc = blockIdx.y;
    const int g = kc >> 3, d0 = (kc & 7) * 64, e0 = et * 64;
    const int tid = threadIdx.x;
    const int tm = tid & 15, te = tid >> 4;

    #pragma unroll
    for (int i = 0; i < 4; ++i) {
        int flat = i * 256 + tid;             // 1024 float4
        int bh = flat >> 4, dq = flat & 15;
        int yrow = (bh >> 3) * 64 + (bh & 7) * 8 + g;
        float4 v = *(const float4*)(Y + (size_t)yrow * 512 + d0 + dq * 4);
        *(float4*)&Al[bh * 64 + ((dq ^ (bh >> 2)) << 2)] = v;
    }
    #pragma unroll
    for (int i = 0; i < 4; ++i) {
        int flat = i * 256 + tid;
        int kk = flat >> 4, eq = flat & 15;
        *(float4*)&Bl[kk * 64 + eq * 4] =
            *(const float4*)(Wv + (size_t)(d0 + kk) * 4096 + g * 512 + e0 + eq * 4);
    }
    __syncthreads();

    float4 acc[4];
    #pragma unroll
    for (int j = 0; j < 4; ++j) acc[j] = make_float4(0.f, 0.f, 0.f, 0.f);

    for (int k = 0; k < 64; ++k) {
        float4 b4 = *(const float4*)&Bl[k * 64 + te * 4];
        const int gcol = (((k >> 2) ^ tm) << 2) + (k & 3);
        #pragma unroll
        for (int j = 0; j < 4; ++j) {
            float a = Al[(tm * 4 + j) * 64 + gcol];
            acc[j].x += a * b4.x; acc[j].y += a * b4.y;
            acc[j].z += a * b4.z; acc[j].w += a * b4.w;
        }
    }
    #pragma unroll
    for (int j = 0; j < 4; ++j)
        *(float4*)&partial[(size_t)kc * 32768 + (tm * 4 + j) * 512 + e0 + te * 4] = acc[j];
}

// ---------------- kernel 9: out = sum_kc partial + sum_g c*bv ------------------------
__global__ void finalize(const float* __restrict__ partial, const float* __restrict__ c,
                         const float* __restrict__ bv, float* __restrict__ out)
{
    int i = blockIdx.x * blockDim.x + threadIdx.x;  // 32768
    int b = i >> 12, h = (i >> 9) & 7, e = i & 511;
    float s = 0.f;
    #pragma unroll
    for (int kc = 0; kc < 64; ++kc) s += partial[(size_t)kc * 32768 + i];
    float bt = 0.f;
    #pragma unroll
    for (int g = 0; g < 8; ++g) bt += c[b * 64 + h * 8 + g] * bv[g * 512 + e];
    out[i] = s + bt;
}

extern "C" void kernel_launch(void* const* d_in, const int* in_sizes, int n_in,
                              void* d_out, int out_size, void* d_ws, size_t ws_size,
                              hipStream_t stream)
{
    const float* queries = (const float*)d_in[0];
    const float* keys    = (const float*)d_in[1];
    const float* values  = (const float*)d_in[2];
    const float* Wq      = (const float*)d_in[3];
    const float* bq      = (const float*)d_in[4];
    const float* Wk      = (const float*)d_in[5];
    const float* bk      = (const float*)d_in[6];
    const float* Wv      = (const float*)d_in[7];
    const float* bv      = (const float*)d_in[8];

    unsigned short* xq  = (unsigned short*)d_ws;
    unsigned short* xk  = xq  + (1u << 21);
    unsigned short* wtq = xk  + (1u << 21);
    unsigned short* wtk = wtq + (1u << 21);
    unsigned short* Q   = wtk + (1u << 21);
    unsigned short* Kb  = Q   + (1u << 24);
    float* P     = (float*)(Kb + (1u << 24));
    float* c     = P + 262144;
    float* ypart = c + 512;
    float* Y     = ypart + 1048576;
    float* part  = Y + 262144;

    convert_x<<<dim3(2048, 1, 2), 256, 0, stream>>>(queries, keys, xq, xk, 2097152);
    transpose_w<<<dim3(128, 16, 2), dim3(32, 8), 0, stream>>>(Wq, Wk, wtq, wtk);
    gemm_bt256<<<dim3(16, 16, 2), 512, 0, stream>>>(xq, xk, wtq, wtk, bq, bk, Q, Kb);
    scores<<<dim3(4096), 64, 0, stream>>>(Q, Kb, P);
    pbkern<<<dim3(8), 256, 0, stream>>>(P, c);
    ykern<<<dim3(8, 8, 4), 256, 0, stream>>>(P, values, ypart);
    yreduce<<<dim3(256), 256, 0, stream>>>(ypart, Y);
    vgemm<<<dim3(8, 64), 256, 0, stream>>>(Y, Wv, part);
    finalize<<<dim3(128), 256, 0, stream>>>(part, c, bv, (float*)d_out);
}

// Round 5
// 104.086 us; speedup vs baseline: 1.0674x; 1.0674x over previous
//
#include <hip/hip_runtime.h>

// B=8, L=512, D=512, H=8. Q/K GEMMs: M=4096, N=4096, K=512 (bf16 MFMA, 256^2 8-phase,
// swapped-operand MFMA + LDS-transposed coalesced epilogue).
// V path (all f32): P' = softmax + 63.875; Y = sum_l P'*Xv (ypart, 4 lc slices);
//   out = Y @ Wv (split-K partials) + (sum_l P')*bv  (pb fused into finalize).

using bf16x8 = __attribute__((ext_vector_type(8))) short;
using f32x4  = __attribute__((ext_vector_type(4))) float;

__device__ __forceinline__ unsigned short f2bf(float f) {
    union { float f; unsigned int u; } c; c.f = f;
    unsigned int u = c.u;
    u += 0x7FFFu + ((u >> 16) & 1u);   // RTNE
    return (unsigned short)(u >> 16);
}
__device__ __forceinline__ float bflo(unsigned int u) {
    union { unsigned int u; float f; } c; c.u = u << 16; return c.f;
}
__device__ __forceinline__ float bfhi(unsigned int u) {
    union { unsigned int u; float f; } c; c.u = u & 0xFFFF0000u; return c.f;
}

#define GLOAD16(gp, lp) __builtin_amdgcn_global_load_lds( \
    (const __attribute__((address_space(1))) unsigned int*)(gp), \
    (__attribute__((address_space(3))) unsigned int*)(lp), 16, 0, 0)

// ---------------- kernel 1: prep = convert Xq/Xk (z=0,1) + transpose Wq/Wk (z=2,3) ---
__global__ __launch_bounds__(256) void prep(
    const float* __restrict__ x0, const float* __restrict__ x1,
    unsigned short* __restrict__ o0, unsigned short* __restrict__ o1,
    const float* __restrict__ w0, const float* __restrict__ w1,
    unsigned short* __restrict__ t0, unsigned short* __restrict__ t1)
{
    const int z = blockIdx.z;
    if (z < 2) {
        const float* src = (z == 0) ? x0 : x1;
        unsigned short* dst = (z == 0) ? o0 : o1;
        int i = (blockIdx.x * 256 + threadIdx.x) * 4;
        float4 v = *(const float4*)(src + i);
        ushort4 o;
        o.x = f2bf(v.x); o.y = f2bf(v.y); o.z = f2bf(v.z); o.w = f2bf(v.w);
        *(ushort4*)(dst + i) = o;
    } else {
        const float* W = (z == 2) ? w0 : w1;
        unsigned short* T = (z == 2) ? t0 : t1;
        __shared__ float tile[32][33];
        const int n0 = (blockIdx.x & 127) * 32, k0 = (blockIdx.x >> 7) * 32;
        const int tx = threadIdx.x & 31, ty = threadIdx.x >> 5;   // (32, 8)
        #pragma unroll
        for (int j = 0; j < 32; j += 8)
            tile[ty + j][tx] = W[(size_t)(k0 + ty + j) * 4096 + n0 + tx];
        __syncthreads();
        #pragma unroll
        for (int j = 0; j < 32; j += 8)
            T[(size_t)(n0 + ty + j) * 512 + k0 + tx] = f2bf(tile[tx][ty + j]);
    }
}

// ---------------- kernel 2: 256^2 8-phase bf16 GEMM, coalesced epilogue --------------
__global__ __launch_bounds__(512) void gemm_bt256(
    const unsigned short* __restrict__ a0, const unsigned short* __restrict__ a1,
    const unsigned short* __restrict__ w0, const unsigned short* __restrict__ w1,
    const float* __restrict__ b0, const float* __restrict__ b1,
    unsigned short* __restrict__ c0, unsigned short* __restrict__ c1)
{
    const unsigned short* A;  const unsigned short* Bt; const float* bias; unsigned short* C;
    if (blockIdx.z == 0) { A = a0; Bt = w0; bias = b0; C = c0; }
    else                 { A = a1; Bt = w1; bias = b1; C = c1; }

    __shared__ __align__(16) unsigned short SH[65536];   // 128 KiB: As(2x32KB) | Bs(2x32KB); reused as C-tile
    unsigned short* As0 = SH;             // As0 + buf*16384 : [256 rows][64 k]
    unsigned short* Bs0 = SH + 32768;

    const int tid  = threadIdx.x;
    const int lane = tid & 63;
    const int wid  = tid >> 6;          // 0..7
    const int wr   = wid >> 2;          // 0..1  (M half)
    const int wn   = wid & 3;           // 0..3  (N quarter)
    const int row0 = blockIdx.y * 256;
    const int n0   = blockIdx.x * 256;
    const int sgran = (lane & 7) ^ (lane >> 3);   // inverse-swizzled source granule

#define STAGE(Pb, Gp, gbase, buf, half, tile)                                     \
    {                                                                             \
        const int rb0 = (half) * 128 + wid * 8;                                   \
        GLOAD16((Gp) + (size_t)((gbase) + rb0 + (lane >> 3)) * 512                \
                       + (tile) * 64 + sgran * 8, (Pb) + (buf) * 16384 + rb0 * 64); \
        const int rb1 = rb0 + 64;                                                 \
        GLOAD16((Gp) + (size_t)((gbase) + rb1 + (lane >> 3)) * 512                \
                       + (tile) * 64 + sgran * 8, (Pb) + (buf) * 16384 + rb1 * 64); \
    }

#define LD_A(c, m, s) (*(const bf16x8*)((const char*)(As0 + (c) * 16384)          \
        + (wr * 128 + (m) * 16 + (lane & 15)) * 128                               \
        + ((((s) * 4 + (lane >> 4)) ^ ((wr * 128 + (m) * 16 + (lane & 15)) & 7)) << 4)))
#define LD_B(c, n, s) (*(const bf16x8*)((const char*)(Bs0 + (c) * 16384)          \
        + (wn * 64 + (n) * 16 + (lane & 15)) * 128                                \
        + ((((s) * 4 + (lane >> 4)) ^ ((wn * 64 + (n) * 16 + (lane & 15)) & 7)) << 4)))

#define BAR() __builtin_amdgcn_s_barrier()
#define VMC4() asm volatile("s_waitcnt vmcnt(4)" ::: "memory")
#define VMC0() asm volatile("s_waitcnt vmcnt(0)" ::: "memory")

    f32x4 acc[8][4];
    #pragma unroll
    for (int m = 0; m < 8; ++m)
        #pragma unroll
        for (int n = 0; n < 4; ++n)
            acc[m][n] = (f32x4){0.f, 0.f, 0.f, 0.f};

    bf16x8 bfr[4][2];
    bf16x8 fa0, fa1, fa2, fa3;

#define LDA_Q(c, q) { fa0 = LD_A(c, 2*(q), 0); fa1 = LD_A(c, 2*(q), 1);           \
                      fa2 = LD_A(c, 2*(q)+1, 0); fa3 = LD_A(c, 2*(q)+1, 1); }
#define LDB_ALL(c) { _Pragma("unroll") for (int n = 0; n < 4; ++n) {              \
                       bfr[n][0] = LD_B(c, n, 0); bfr[n][1] = LD_B(c, n, 1); } }
    // swapped operands: D-frag holds (row = lane&15 of A-rows, 4 consecutive C-cols per reg)
#define MFMA_Q(q) { __builtin_amdgcn_s_setprio(1);                                \
    _Pragma("unroll") for (int n = 0; n < 4; ++n) {                               \
      acc[2*(q)][n]   = __builtin_amdgcn_mfma_f32_16x16x32_bf16(bfr[n][0], fa0, acc[2*(q)][n],   0,0,0); \
      acc[2*(q)][n]   = __builtin_amdgcn_mfma_f32_16x16x32_bf16(bfr[n][1], fa1, acc[2*(q)][n],   0,0,0); \
      acc[2*(q)+1][n] = __builtin_amdgcn_mfma_f32_16x16x32_bf16(bfr[n][0], fa2, acc[2*(q)+1][n], 0,0,0); \
      acc[2*(q)+1][n] = __builtin_amdgcn_mfma_f32_16x16x32_bf16(bfr[n][1], fa3, acc[2*(q)+1][n], 0,0,0); } \
    __builtin_amdgcn_s_setprio(0); }

    // prologue: buf0.B(t0), buf0.A(t0), buf1.B(t1)
    STAGE(Bs0, Bt, n0, 0, 0, 0); STAGE(Bs0, Bt, n0, 0, 1, 0);
    STAGE(As0, A,  row0, 0, 0, 0); STAGE(As0, A,  row0, 0, 1, 0);
    STAGE(Bs0, Bt, n0, 1, 0, 1); STAGE(Bs0, Bt, n0, 1, 1, 1);
    VMC4();
    BAR();

    for (int i = 0; i < 4; ++i) {
        const int t1 = 2 * i + 1, t2 = 2 * i + 2, t3 = 2 * i + 3;
        const bool s2 = (t2 < 8), s3 = (t3 < 8);

        LDA_Q(0, 0); LDB_ALL(0);
        STAGE(As0, A, row0, 1, 0, t1);
        BAR(); MFMA_Q(0); BAR();

        LDA_Q(0, 1);
        STAGE(As0, A, row0, 1, 1, t1);
        BAR(); MFMA_Q(1); BAR();

        LDA_Q(0, 2);
        if (s2) STAGE(Bs0, Bt, n0, 0, 0, t2);
        BAR(); MFMA_Q(2); BAR();

        LDA_Q(0, 3);
        if (s2) STAGE(Bs0, Bt, n0, 0, 1, t2);
        BAR(); MFMA_Q(3);
        if (i < 3) { VMC4(); } else { VMC0(); }
        BAR();

        LDA_Q(1, 0); LDB_ALL(1);
        if (s2) STAGE(As0, A, row0, 0, 0, t2);
        BAR(); MFMA_Q(0); BAR();

        LDA_Q(1, 1);
        if (s2) STAGE(As0, A, row0, 0, 1, t2);
        BAR(); MFMA_Q(1); BAR();

        LDA_Q(1, 2);
        if (s3) STAGE(Bs0, Bt, n0, 1, 0, t3);
        BAR(); MFMA_Q(2); BAR();

        LDA_Q(1, 3);
        if (s3) STAGE(Bs0, Bt, n0, 1, 1, t3);
        BAR(); MFMA_Q(3);
        if (i < 3) { VMC4(); }
        BAR();
    }

    // ---- epilogue: acc -> swizzled LDS tile (256x256 bf16 = 128 KB) -> coalesced C ----
    // swapped-D frag: C-row = tile-row wr*128+m*16+(lane&15); C-cols = wn*64+n*16+q*4+r, q=lane>>4
    {
        const int q  = lane >> 4;
        const int tr = wr * 128 + (lane & 15);    // + m*16
        #pragma unroll
        for (int n = 0; n < 4; ++n) {
            float4 bb = *(const float4*)(bias + n0 + wn * 64 + n * 16 + q * 4);
            #pragma unroll
            for (int m = 0; m < 8; ++m) {
                const int trm = tr + m * 16;
                const int g16 = wn * 8 + n * 2 + (q >> 1);            // 16B granule in row
                unsigned long long pk =
                      (unsigned long long)f2bf(acc[m][n][0] + bb.x)
                    | ((unsigned long long)f2bf(acc[m][n][1] + bb.y) << 16)
                    | ((unsigned long long)f2bf(acc[m][n][2] + bb.z) << 32)
                    | ((unsigned long long)f2bf(acc[m][n][3] + bb.w) << 48);
                *(unsigned long long*)((char*)SH + trm * 512
                    + ((g16 ^ (trm & 7)) << 4) + (q & 1) * 8) = pk;
            }
        }
        BAR();
        #pragma unroll
        for (int it = 0; it < 16; ++it) {
            const int f = it * 512 + tid;         // 8192 chunks of 16B
            const int rr = f >> 5, gg = f & 31;
            uint4 v = *(const uint4*)((const char*)SH + rr * 512 + ((gg ^ (rr & 7)) << 4));
            *(uint4*)(C + (size_t)(row0 + rr) * 4096 + n0 + gg * 8) = v;
        }
    }
#undef STAGE
#undef LD_A
#undef LD_B
}

// ---------------- kernel 3: scores + softmax -> P' = p + 63.875 ---------------------
__global__ __launch_bounds__(64) void scores(const unsigned short* __restrict__ Q,
                                             const unsigned short* __restrict__ K,
                                             float* __restrict__ P)
{
    __shared__ __align__(16) unsigned short qs[8 * 520];
    __shared__ __align__(16) unsigned short ks[8 * 520];
    const int r = blockIdx.x;        // b*512 + l
    const int lane = threadIdx.x;    // 64
    const unsigned short* qrow = Q + (size_t)r * 4096;
    const unsigned short* krow = K + (size_t)r * 4096;
    #pragma unroll
    for (int m = 0; m < 8; ++m) {
        *(uint4*)(&qs[m * 520 + lane * 8]) = *(const uint4*)(qrow + m * 512 + lane * 8);
        *(uint4*)(&ks[m * 520 + lane * 8]) = *(const uint4*)(krow + m * 512 + lane * 8);
    }
    __syncthreads();

    const int h = lane >> 3, g = lane & 7;
    const unsigned short* qh = &qs[h * 520];
    const unsigned short* kg = &ks[g * 520];
    float dot = 0.f;
    #pragma unroll 4
    for (int m = 0; m < 64; ++m) {
        uint4 qa = *(const uint4*)(qh + m * 8);
        uint4 ka = *(const uint4*)(kg + m * 8);
        dot += bflo(qa.x) * bflo(ka.x) + bfhi(qa.x) * bfhi(ka.x);
        dot += bflo(qa.y) * bflo(ka.y) + bfhi(qa.y) * bfhi(ka.y);
        dot += bflo(qa.z) * bflo(ka.z) + bfhi(qa.z) * bfhi(ka.z);
        dot += bflo(qa.w) * bflo(ka.w) + bfhi(qa.w) * bfhi(ka.w);
    }
    float s = dot * 0.04419417382415922f;   // 1/sqrt(512)
    float mx = s;
    mx = fmaxf(mx, __shfl_xor(mx, 1));
    mx = fmaxf(mx, __shfl_xor(mx, 2));
    mx = fmaxf(mx, __shfl_xor(mx, 4));
    float e = __expf(s - mx);
    float sm = e;
    sm += __shfl_xor(sm, 1);
    sm += __shfl_xor(sm, 2);
    sm += __shfl_xor(sm, 4);
    P[(size_t)r * 64 + lane] = e / sm + 63.875f;
}

// ---------------- kernel 4: ypart[lc,b,hg,d] = sum_{l in chunk} P' * Xv --------------
__global__ __launch_bounds__(256) void ykern(const float* __restrict__ P,
                                             const float* __restrict__ Xv,
                                             float* __restrict__ ypart)
{
    __shared__ float Pl[128 * 64];
    __shared__ float Xl[128 * 64];
    const int b = blockIdx.x, dt = blockIdx.y, lc = blockIdx.z;
    const int tid = threadIdx.x;
    const int tm = tid & 15, te = tid >> 4;

    const float* Pg = P + ((size_t)b * 512 + lc * 128) * 64;
    #pragma unroll
    for (int i = 0; i < 8; ++i)
        *(float4*)&Pl[(i * 256 + tid) * 4] = *(const float4*)(Pg + (size_t)(i * 256 + tid) * 4);
    const float* Xg = Xv + ((size_t)b * 512 + lc * 128) * 512 + dt * 64;
    #pragma unroll
    for (int i = 0; i < 8; ++i) {
        int flat = i * 256 + tid;            // 2048 float4 = 128 rows x 16
        int r = flat >> 4, q = flat & 15;
        *(float4*)&Xl[r * 64 + q * 4] = *(const float4*)(Xg + (size_t)r * 512 + q * 4);
    }
    __syncthreads();

    float4 acc[4];
    #pragma unroll
    for (int i = 0; i < 4; ++i) acc[i] = make_float4(0.f, 0.f, 0.f, 0.f);

    for (int l = 0; l < 128; ++l) {
        float4 pv = *(const float4*)&Pl[l * 64 + tm * 4];
        float4 xv = *(const float4*)&Xl[l * 64 + te * 4];
        acc[0].x += pv.x * xv.x; acc[0].y += pv.x * xv.y; acc[0].z += pv.x * xv.z; acc[0].w += pv.x * xv.w;
        acc[1].x += pv.y * xv.x; acc[1].y += pv.y * xv.y; acc[1].z += pv.y * xv.z; acc[1].w += pv.y * xv.w;
        acc[2].x += pv.z * xv.x; acc[2].y += pv.z * xv.y; acc[2].z += pv.z * xv.z; acc[2].w += pv.z * xv.w;
        acc[3].x += pv.w * xv.x; acc[3].y += pv.w * xv.y; acc[3].z += pv.w * xv.z; acc[3].w += pv.w * xv.w;
    }
    #pragma unroll
    for (int i = 0; i < 4; ++i)
        *(float4*)&ypart[(((size_t)lc * 8 + b) * 64 + tm * 4 + i) * 512 + dt * 64 + te * 4] = acc[i];
}

// ---------------- kernel 5: split-K vgemm (yreduce fused into A-stage) ---------------
__global__ __launch_bounds__(256) void vgemm(const float* __restrict__ ypart,
                                             const float* __restrict__ Wv,
                                             float* __restrict__ partial)
{
    __shared__ float Al[64 * 64];   // [bh][d], granule-XOR swizzled
    __shared__ float Bl[64 * 64];   // [kk][e] linear
    const int et = blockIdx.x, kc = blockIdx.y;
    const int g = kc >> 3, d0 = (kc & 7) * 64, e0 = et * 64;
    const int tid = threadIdx.x;
    const int tm = tid & 15, te = tid >> 4;

    #pragma unroll
    for (int i = 0; i < 4; ++i) {
        int flat = i * 256 + tid;             // 1024 float4
        int bh = flat >> 4, dq = flat & 15;
        int yrow = (bh >> 3) * 64 + (bh & 7) * 8 + g;   // [b][hg] row of Y
        size_t base = ((size_t)(yrow >> 6) * 64 + (yrow & 63)) * 512 + d0 + dq * 4;
        float4 v = *(const float4*)(ypart + base);
        #pragma unroll
        for (int lc = 1; lc < 4; ++lc) {
            float4 t = *(const float4*)(ypart + (size_t)lc * 262144 + base);
            v.x += t.x; v.y += t.y; v.z += t.z; v.w += t.w;
        }
        *(float4*)&Al[bh * 64 + ((dq ^ (bh >> 2)) << 2)] = v;
    }
    #pragma unroll
    for (int i = 0; i < 4; ++i) {
        int flat = i * 256 + tid;
        int kk = flat >> 4, eq = flat & 15;
        *(float4*)&Bl[kk * 64 + eq * 4] =
            *(const float4*)(Wv + (size_t)(d0 + kk) * 4096 + g * 512 + e0 + eq * 4);
    }
    __syncthreads();

    float4 acc[4];
    #pragma unroll
    for (int j = 0; j < 4; ++j) acc[j] = make_float4(0.f, 0.f, 0.f, 0.f);

    for (int k = 0; k < 64; ++k) {
        float4 b4 = *(const float4*)&Bl[k * 64 + te * 4];
        const int gcol = (((k >> 2) ^ tm) << 2) + (k & 3);
        #pragma unroll
        for (int j = 0; j < 4; ++j) {
            float a = Al[(tm * 4 + j) * 64 + gcol];
            acc[j].x += a * b4.x; acc[j].y += a * b4.y;
            acc[j].z += a * b4.z; acc[j].w += a * b4.w;
        }
    }
    #pragma unroll
    for (int j = 0; j < 4; ++j)
        *(float4*)&partial[(size_t)kc * 32768 + (tm * 4 + j) * 512 + e0 + te * 4] = acc[j];
}

// ---------------- kernel 6: finalize (pb fused): out = sum_kc partial + sum_g c*bv ---
__global__ __launch_bounds__(256) void finalize(const float* __restrict__ partial,
                                                const float* __restrict__ P,
                                                const float* __restrict__ bv,
                                                float* __restrict__ out)
{
    __shared__ float red[64];
    __shared__ float csh[8];
    const int blk = blockIdx.x;          // 128 blocks: (b,h) x half-e
    const int tid = threadIdx.x;
    const int b = blk >> 4, h = (blk >> 1) & 7;
    const int e = (blk & 1) * 256 + tid;

    if (tid < 64) {                      // c[g] = sum_l P'[b,l,h*8+g]
        const int g = tid & 7, seg = tid >> 3;
        float s = 0.f;
        const float* Pp = P + ((size_t)b * 512 + seg * 64) * 64 + h * 8 + g;
        #pragma unroll 8
        for (int j = 0; j < 64; ++j) s += Pp[j * 64];
        red[tid] = s;
    }
    __syncthreads();
    if (tid < 8) {
        float s = 0.f;
        #pragma unroll
        for (int q = 0; q < 8; ++q) s += red[q * 8 + tid];
        csh[tid] = s;
    }
    __syncthreads();

    const int i = ((b * 8 + h) << 9) + e;
    float s = 0.f;
    #pragma unroll
    for (int kc = 0; kc < 64; ++kc) s += partial[(size_t)kc * 32768 + i];
    float bt = 0.f;
    #pragma unroll
    for (int g = 0; g < 8; ++g) bt += csh[g] * bv[g * 512 + e];
    out[i] = s + bt;
}

extern "C" void kernel_launch(void* const* d_in, const int* in_sizes, int n_in,
                              void* d_out, int out_size, void* d_ws, size_t ws_size,
                              hipStream_t stream)
{
    const float* queries = (const float*)d_in[0];
    const float* keys    = (const float*)d_in[1];
    const float* values  = (const float*)d_in[2];
    const float* Wq      = (const float*)d_in[3];
    const float* bq      = (const float*)d_in[4];
    const float* Wk      = (const float*)d_in[5];
    const float* bk      = (const float*)d_in[6];
    const float* Wv      = (const float*)d_in[7];
    const float* bv      = (const float*)d_in[8];

    unsigned short* xq  = (unsigned short*)d_ws;
    unsigned short* xk  = xq  + (1u << 21);
    unsigned short* wtq = xk  + (1u << 21);
    unsigned short* wtk = wtq + (1u << 21);
    unsigned short* Q   = wtk + (1u << 21);
    unsigned short* Kb  = Q   + (1u << 24);
    float* P     = (float*)(Kb + (1u << 24));
    float* ypart = P + 262144;
    float* part  = ypart + 4 * 262144;

    prep<<<dim3(2048, 1, 4), 256, 0, stream>>>(queries, keys, xq, xk, Wq, Wk, wtq, wtk);
    gemm_bt256<<<dim3(16, 16, 2), 512, 0, stream>>>(xq, xk, wtq, wtk, bq, bk, Q, Kb);
    scores<<<dim3(4096), 64, 0, stream>>>(Q, Kb, P);
    ykern<<<dim3(8, 8, 4), 256, 0, stream>>>(P, values, ypart);
    vgemm<<<dim3(8, 64), 256, 0, stream>>>(ypart, Wv, part);
    finalize<<<dim3(128), 256, 0, stream>>>(part, P, bv, (float*)d_out);
}

// Round 6
// 94.681 us; speedup vs baseline: 1.1734x; 1.0993x over previous
//
#include <hip/hip_runtime.h>

// B=8, L=512, D=512, H=8. Q/K GEMMs: M=4096, N=4096, K=512 (bf16 MFMA, 256^2 8-phase,
// swapped-operand MFMA + LDS-transposed coalesced FP8 epilogue).
// Q,K stored fp8-e4m3; scores use fp8 MFMA (16x16x32) on (l-parity,h) packed tiles.
// V path (all f32): P' = softmax + 63.875; Y = sum_l P'*Xv; out = Y @ Wv + c*bv.

using bf16x8 = __attribute__((ext_vector_type(8))) short;
using f32x4  = __attribute__((ext_vector_type(4))) float;

__device__ __forceinline__ unsigned short f2bf(float f) {
    union { float f; unsigned int u; } c; c.f = f;
    unsigned int u = c.u;
    u += 0x7FFFu + ((u >> 16) & 1u);   // RTNE
    return (unsigned short)(u >> 16);
}
__device__ __forceinline__ float bflo(unsigned int u) {
    union { unsigned int u; float f; } c; c.u = u << 16; return c.f;
}
__device__ __forceinline__ float bfhi(unsigned int u) {
    union { unsigned int u; float f; } c; c.u = u & 0xFFFF0000u; return c.f;
}
// f32 -> fp8 e4m3fn (OCP), RTNE, flush |x|<2^-6 to 0, clamp to 448.
__device__ __forceinline__ unsigned int f2fp8(float f) {
    union { float f; unsigned int u; } c; c.f = f;
    unsigned int u = c.u;
    unsigned int s = (u >> 24) & 0x80u;
    unsigned int a = u & 0x7FFFFFFFu;
    if (a < 0x3C800000u) return s;                 // |f| < 2^-6 -> signed zero
    if (a > 0x43E00000u) a = 0x43E00000u;          // clamp to 448
    unsigned int lsb = (a >> 20) & 1u;
    a += 0x0007FFFFu + lsb;                        // RTNE at mantissa bit 20
    unsigned int e = ((a >> 23) & 0xFFu) - 120u;   // rebias 127 -> 7
    unsigned int m = (a >> 20) & 7u;
    return s | (e << 3) | m;
}

#define GLOAD16(gp, lp) __builtin_amdgcn_global_load_lds( \
    (const __attribute__((address_space(1))) unsigned int*)(gp), \
    (__attribute__((address_space(3))) unsigned int*)(lp), 16, 0, 0)

// ---------------- kernel 1: prep = convert Xq/Xk (z=0,1) + transpose Wq/Wk (z=2,3) ---
__global__ __launch_bounds__(256) void prep(
    const float* __restrict__ x0, const float* __restrict__ x1,
    unsigned short* __restrict__ o0, unsigned short* __restrict__ o1,
    const float* __restrict__ w0, const float* __restrict__ w1,
    unsigned short* __restrict__ t0, unsigned short* __restrict__ t1)
{
    const int z = blockIdx.z;
    if (z < 2) {
        const float* src = (z == 0) ? x0 : x1;
        unsigned short* dst = (z == 0) ? o0 : o1;
        int i = (blockIdx.x * 256 + threadIdx.x) * 4;
        float4 v = *(const float4*)(src + i);
        ushort4 o;
        o.x = f2bf(v.x); o.y = f2bf(v.y); o.z = f2bf(v.z); o.w = f2bf(v.w);
        *(ushort4*)(dst + i) = o;
    } else {
        const float* W = (z == 2) ? w0 : w1;
        unsigned short* T = (z == 2) ? t0 : t1;
        __shared__ float tile[32][33];
        const int n0 = (blockIdx.x & 127) * 32, k0 = (blockIdx.x >> 7) * 32;
        const int tx = threadIdx.x & 31, ty = threadIdx.x >> 5;   // (32, 8)
        #pragma unroll
        for (int j = 0; j < 32; j += 8)
            tile[ty + j][tx] = W[(size_t)(k0 + ty + j) * 4096 + n0 + tx];
        __syncthreads();
        #pragma unroll
        for (int j = 0; j < 32; j += 8)
            T[(size_t)(n0 + ty + j) * 512 + k0 + tx] = f2bf(tile[tx][ty + j]);
    }
}

// ---------------- kernel 2: 256^2 8-phase bf16 GEMM, fp8 coalesced epilogue ----------
__global__ __launch_bounds__(512) void gemm_bt256(
    const unsigned short* __restrict__ a0, const unsigned short* __restrict__ a1,
    const unsigned short* __restrict__ w0, const unsigned short* __restrict__ w1,
    const float* __restrict__ b0, const float* __restrict__ b1,
    unsigned char* __restrict__ c0, unsigned char* __restrict__ c1)
{
    const unsigned short* A;  const unsigned short* Bt; const float* bias; unsigned char* C;
    if (blockIdx.z == 0) { A = a0; Bt = w0; bias = b0; C = c0; }
    else                 { A = a1; Bt = w1; bias = b1; C = c1; }

    __shared__ __align__(16) unsigned short SH[65536];   // 128 KiB: As(2x32KB) | Bs(2x32KB)
    unsigned short* As0 = SH;
    unsigned short* Bs0 = SH + 32768;

    const int tid  = threadIdx.x;
    const int lane = tid & 63;
    const int wid  = tid >> 6;
    const int wr   = wid >> 2;
    const int wn   = wid & 3;
    // XCD-chunked bijective swizzle: each XCD gets a 4x8 rect of (n,m)-tiles
    const int linb = blockIdx.y * 16 + blockIdx.x;
    const int swz  = (linb & 7) * 32 + (linb >> 3);
    const int bx   = (swz >> 6) * 4 + (swz & 3);
    const int by   = (swz >> 2) & 15;
    const int row0 = by * 256;
    const int n0   = bx * 256;
    const int sgran = (lane & 7) ^ (lane >> 3);

#define STAGE(Pb, Gp, gbase, buf, half, tile)                                     \
    {                                                                             \
        const int rb0 = (half) * 128 + wid * 8;                                   \
        GLOAD16((Gp) + (size_t)((gbase) + rb0 + (lane >> 3)) * 512                \
                       + (tile) * 64 + sgran * 8, (Pb) + (buf) * 16384 + rb0 * 64); \
        const int rb1 = rb0 + 64;                                                 \
        GLOAD16((Gp) + (size_t)((gbase) + rb1 + (lane >> 3)) * 512                \
                       + (tile) * 64 + sgran * 8, (Pb) + (buf) * 16384 + rb1 * 64); \
    }

#define LD_A(c, m, s) (*(const bf16x8*)((const char*)(As0 + (c) * 16384)          \
        + (wr * 128 + (m) * 16 + (lane & 15)) * 128                               \
        + ((((s) * 4 + (lane >> 4)) ^ ((wr * 128 + (m) * 16 + (lane & 15)) & 7)) << 4)))
#define LD_B(c, n, s) (*(const bf16x8*)((const char*)(Bs0 + (c) * 16384)          \
        + (wn * 64 + (n) * 16 + (lane & 15)) * 128                                \
        + ((((s) * 4 + (lane >> 4)) ^ ((wn * 64 + (n) * 16 + (lane & 15)) & 7)) << 4)))

#define BAR() __builtin_amdgcn_s_barrier()
#define VMC4() asm volatile("s_waitcnt vmcnt(4)" ::: "memory")
#define VMC0() asm volatile("s_waitcnt vmcnt(0)" ::: "memory")

    f32x4 acc[8][4];
    #pragma unroll
    for (int m = 0; m < 8; ++m)
        #pragma unroll
        for (int n = 0; n < 4; ++n)
            acc[m][n] = (f32x4){0.f, 0.f, 0.f, 0.f};

    bf16x8 bfr[4][2];
    bf16x8 fa0, fa1, fa2, fa3;

#define LDA_Q(c, q) { fa0 = LD_A(c, 2*(q), 0); fa1 = LD_A(c, 2*(q), 1);           \
                      fa2 = LD_A(c, 2*(q)+1, 0); fa3 = LD_A(c, 2*(q)+1, 1); }
#define LDB_ALL(c) { _Pragma("unroll") for (int n = 0; n < 4; ++n) {              \
                       bfr[n][0] = LD_B(c, n, 0); bfr[n][1] = LD_B(c, n, 1); } }
#define MFMA_Q(q) { __builtin_amdgcn_s_setprio(1);                                \
    _Pragma("unroll") for (int n = 0; n < 4; ++n) {                               \
      acc[2*(q)][n]   = __builtin_amdgcn_mfma_f32_16x16x32_bf16(bfr[n][0], fa0, acc[2*(q)][n],   0,0,0); \
      acc[2*(q)][n]   = __builtin_amdgcn_mfma_f32_16x16x32_bf16(bfr[n][1], fa1, acc[2*(q)][n],   0,0,0); \
      acc[2*(q)+1][n] = __builtin_amdgcn_mfma_f32_16x16x32_bf16(bfr[n][0], fa2, acc[2*(q)+1][n], 0,0,0); \
      acc[2*(q)+1][n] = __builtin_amdgcn_mfma_f32_16x16x32_bf16(bfr[n][1], fa3, acc[2*(q)+1][n], 0,0,0); } \
    __builtin_amdgcn_s_setprio(0); }

    STAGE(Bs0, Bt, n0, 0, 0, 0); STAGE(Bs0, Bt, n0, 0, 1, 0);
    STAGE(As0, A,  row0, 0, 0, 0); STAGE(As0, A,  row0, 0, 1, 0);
    STAGE(Bs0, Bt, n0, 1, 0, 1); STAGE(Bs0, Bt, n0, 1, 1, 1);
    VMC4();
    BAR();

    for (int i = 0; i < 4; ++i) {
        const int t1 = 2 * i + 1, t2 = 2 * i + 2, t3 = 2 * i + 3;
        const bool s2 = (t2 < 8), s3 = (t3 < 8);

        LDA_Q(0, 0); LDB_ALL(0);
        STAGE(As0, A, row0, 1, 0, t1);
        BAR(); MFMA_Q(0); BAR();

        LDA_Q(0, 1);
        STAGE(As0, A, row0, 1, 1, t1);
        BAR(); MFMA_Q(1); BAR();

        LDA_Q(0, 2);
        if (s2) STAGE(Bs0, Bt, n0, 0, 0, t2);
        BAR(); MFMA_Q(2); BAR();

        LDA_Q(0, 3);
        if (s2) STAGE(Bs0, Bt, n0, 0, 1, t2);
        BAR(); MFMA_Q(3);
        if (i < 3) { VMC4(); } else { VMC0(); }
        BAR();

        LDA_Q(1, 0); LDB_ALL(1);
        if (s2) STAGE(As0, A, row0, 0, 0, t2);
        BAR(); MFMA_Q(0); BAR();

        LDA_Q(1, 1);
        if (s2) STAGE(As0, A, row0, 0, 1, t2);
        BAR(); MFMA_Q(1); BAR();

        LDA_Q(1, 2);
        if (s3) STAGE(Bs0, Bt, n0, 1, 0, t3);
        BAR(); MFMA_Q(2); BAR();

        LDA_Q(1, 3);
        if (s3) STAGE(Bs0, Bt, n0, 1, 1, t3);
        BAR(); MFMA_Q(3);
        if (i < 3) { VMC4(); }
        BAR();
    }

    // ---- epilogue: acc -> swizzled fp8 LDS tile (256x256 = 64 KB) -> coalesced C ----
    // swapped-D frag: C-row = wr*128+m*16+(lane&15); C-cols = wn*64+n*16+q*4+r, q=lane>>4
    {
        const int q  = lane >> 4;
        const int tr = wr * 128 + (lane & 15);
        unsigned char* SB = (unsigned char*)SH;
        #pragma unroll
        for (int n = 0; n < 4; ++n) {
            float4 bb = *(const float4*)(bias + n0 + wn * 64 + n * 16 + q * 4);
            const int g16 = wn * 4 + n;               // 16B granule index (16 per 256B row)
            #pragma unroll
            for (int m = 0; m < 8; ++m) {
                const int trm = tr + m * 16;
                unsigned int pk = f2fp8(acc[m][n][0] + bb.x)
                                | (f2fp8(acc[m][n][1] + bb.y) << 8)
                                | (f2fp8(acc[m][n][2] + bb.z) << 16)
                                | (f2fp8(acc[m][n][3] + bb.w) << 24);
                *(unsigned int*)(SB + trm * 256 + ((g16 ^ (trm & 15)) << 4) + q * 4) = pk;
            }
        }
        BAR();
        #pragma unroll
        for (int it = 0; it < 8; ++it) {
            const int f = it * 512 + tid;             // 4096 chunks of 16B
            const int rr = f >> 4, gg = f & 15;
            uint4 v = *(const uint4*)(SB + rr * 256 + ((gg ^ (rr & 15)) << 4));
            *(uint4*)(C + (size_t)(row0 + rr) * 4096 + gg * 16 + n0) = v;
        }
    }
#undef STAGE
#undef LD_A
#undef LD_B
}

// ---------------- kernel 3: fp8-MFMA scores + softmax + pb-partials ------------------
// block = (b, lc of 8 l's), 256 thr (4 waves). Wave w owns l-pair {l0+2w, l0+2w+1}.
// A rows / B cols = (l-parity, h): 16x16x32 fp8 MFMA over e=512 (16 k-tiles).
// D[row][col] useful iff row-parity == col-parity; softmax over g = lane&7 via shfl.
__global__ __launch_bounds__(256) void mfscores(const unsigned char* __restrict__ Q,
                                                const unsigned char* __restrict__ K,
                                                float* __restrict__ P,
                                                float* __restrict__ pbpart)
{
    __shared__ float Pl[8 * 64];
    const int b = blockIdx.x, lc = blockIdx.y;       // (8, 64)
    const int tid = threadIdx.x, lane = tid & 63, w = tid >> 6;
    const int l0 = lc * 8;

    const int colr = lane & 15;                       // A-row / B-col index
    const int ko   = lane >> 4;                       // k-octet within k-tile
    const int la   = l0 + w * 2 + (colr >> 3);        // this row/col's l
    const int hh   = colr & 7;
    const unsigned char* qrow = Q + (size_t)(b * 512 + la) * 4096 + hh * 512 + ko * 8;
    const unsigned char* krow = K + (size_t)(b * 512 + la) * 4096 + hh * 512 + ko * 8;

    f32x4 acc = (f32x4){0.f, 0.f, 0.f, 0.f};
    #pragma unroll
    for (int kt = 0; kt < 16; ++kt) {
        long long av = *(const long long*)(qrow + kt * 32);
        long long bv = *(const long long*)(krow + kt * 32);
        acc = __builtin_amdgcn_mfma_f32_16x16x32_fp8_fp8(av, bv, acc, 0, 0, 0);
    }

    // D: col = lane&15, row = (lane>>4)*4 + r. row-parity = ko>>1, col-parity = (lane>>3)&1.
    const int lpr = ko >> 1;
    const int lpc = (lane >> 3) & 1;
    #pragma unroll
    for (int r = 0; r < 4; ++r) {
        float s = acc[r] * 0.04419417382415922f;      // 1/sqrt(512)
        float m = s;
        m = fmaxf(m, __shfl_xor(m, 1));
        m = fmaxf(m, __shfl_xor(m, 2));
        m = fmaxf(m, __shfl_xor(m, 4));
        float e = __expf(s - m);
        float ss = e;
        ss += __shfl_xor(ss, 1);
        ss += __shfl_xor(ss, 2);
        ss += __shfl_xor(ss, 4);
        float p = e / ss + 63.875f;                   // fold uniform part
        if (lpr == lpc)
            Pl[(w * 2 + lpr) * 64 + ((ko & 1) * 4 + r) * 8 + (lane & 7)] = p;
    }
    __syncthreads();

    {   // write P (8 x 64) coalesced
        const int l = tid >> 5, off = (tid & 31) * 2;
        float2 v = *(const float2*)&Pl[l * 64 + off];
        *(float2*)(P + (size_t)(b * 512 + l0 + l) * 64 + off) = v;
    }
    if (tid < 64) {                                   // pb partial over this block's 8 l's
        float s = 0.f;
        #pragma unroll
        for (int l = 0; l < 8; ++l) s += Pl[l * 64 + tid];
        pbpart[((size_t)b * 64 + lc) * 64 + tid] = s;
    }
}

// ---------------- kernel 4: ypart[lc,b,hg,d] = sum_{l in chunk} P' * Xv --------------
__global__ __launch_bounds__(256) void ykern(const float* __restrict__ P,
                                             const float* __restrict__ Xv,
                                             float* __restrict__ ypart)
{
    __shared__ float Pl[128 * 64];
    __shared__ float Xl[128 * 64];
    const int b = blockIdx.x, dt = blockIdx.y, lc = blockIdx.z;
    const int tid = threadIdx.x;
    const int tm = tid & 15, te = tid >> 4;

    const float* Pg = P + ((size_t)b * 512 + lc * 128) * 64;
    #pragma unroll
    for (int i = 0; i < 8; ++i)
        *(float4*)&Pl[(i * 256 + tid) * 4] = *(const float4*)(Pg + (size_t)(i * 256 + tid) * 4);
    const float* Xg = Xv + ((size_t)b * 512 + lc * 128) * 512 + dt * 64;
    #pragma unroll
    for (int i = 0; i < 8; ++i) {
        int flat = i * 256 + tid;
        int r = flat >> 4, q = flat & 15;
        *(float4*)&Xl[r * 64 + q * 4] = *(const float4*)(Xg + (size_t)r * 512 + q * 4);
    }
    __syncthreads();

    float4 acc[4];
    #pragma unroll
    for (int i = 0; i < 4; ++i) acc[i] = make_float4(0.f, 0.f, 0.f, 0.f);

    for (int l = 0; l < 128; ++l) {
        float4 pv = *(const float4*)&Pl[l * 64 + tm * 4];
        float4 xv = *(const float4*)&Xl[l * 64 + te * 4];
        acc[0].x += pv.x * xv.x; acc[0].y += pv.x * xv.y; acc[0].z += pv.x * xv.z; acc[0].w += pv.x * xv.w;
        acc[1].x += pv.y * xv.x; acc[1].y += pv.y * xv.y; acc[1].z += pv.y * xv.z; acc[1].w += pv.y * xv.w;
        acc[2].x += pv.z * xv.x; acc[2].y += pv.z * xv.y; acc[2].z += pv.z * xv.z; acc[2].w += pv.z * xv.w;
        acc[3].x += pv.w * xv.x; acc[3].y += pv.w * xv.y; acc[3].z += pv.w * xv.z; acc[3].w += pv.w * xv.w;
    }
    #pragma unroll
    for (int i = 0; i < 4; ++i)
        *(float4*)&ypart[(((size_t)lc * 8 + b) * 64 + tm * 4 + i) * 512 + dt * 64 + te * 4] = acc[i];
}

// ---------------- kernel 5: split-K vgemm (yreduce fused into A-stage) ---------------
__global__ __launch_bounds__(256) void vgemm(const float* __restrict__ ypart,
                                             const float* __restrict__ Wv,
                                             float* __restrict__ partial)
{
    __shared__ float Al[64 * 64];
    __shared__ float Bl[64 * 64];
    const int et = blockIdx.x, kc = blockIdx.y;
    const int g = kc >> 3, d0 = (kc & 7) * 64, e0 = et * 64;
    const int tid = threadIdx.x;
    const int tm = tid & 15, te = tid >> 4;

    #pragma unroll
    for (int i = 0; i < 4; ++i) {
        int flat = i * 256 + tid;
        int bh = flat >> 4, dq = flat & 15;
        int yrow = (bh >> 3) * 64 + (bh & 7) * 8 + g;
        size_t base = ((size_t)(yrow >> 6) * 64 + (yrow & 63)) * 512 + d0 + dq * 4;
        float4 v = *(const float4*)(ypart + base);
        #pragma unroll
        for (int lc = 1; lc < 4; ++lc) {
            float4 t = *(const float4*)(ypart + (size_t)lc * 262144 + base);
            v.x += t.x; v.y += t.y; v.z += t.z; v.w += t.w;
        }
        *(float4*)&Al[bh * 64 + ((dq ^ (bh >> 2)) << 2)] = v;
    }
    #pragma unroll
    for (int i = 0; i < 4; ++i) {
        int flat = i * 256 + tid;
        int kk = flat >> 4, eq = flat & 15;
        *(float4*)&Bl[kk * 64 + eq * 4] =
            *(const float4*)(Wv + (size_t)(d0 + kk) * 4096 + g * 512 + e0 + eq * 4);
    }
    __syncthreads();

    float4 acc[4];
    #pragma unroll
    for (int j = 0; j < 4; ++j) acc[j] = make_float4(0.f, 0.f, 0.f, 0.f);

    for (int k = 0; k < 64; ++k) {
        float4 b4 = *(const float4*)&Bl[k * 64 + te * 4];
        const int gcol = (((k >> 2) ^ tm) << 2) + (k & 3);
        #pragma unroll
        for (int j = 0; j < 4; ++j) {
            float a = Al[(tm * 4 + j) * 64 + gcol];
            acc[j].x += a * b4.x; acc[j].y += a * b4.y;
            acc[j].z += a * b4.z; acc[j].w += a * b4.w;
        }
    }
    #pragma unroll
    for (int j = 0; j < 4; ++j)
        *(float4*)&partial[(size_t)kc * 32768 + (tm * 4 + j) * 512 + e0 + te * 4] = acc[j];
}

// ---------------- kernel 6: finalize: out = sum_kc partial + sum_g c*bv --------------
__global__ __launch_bounds__(256) void finalize(const float* __restrict__ partial,
                                                const float* __restrict__ pbpart,
                                                const float* __restrict__ bv,
                                                float* __restrict__ out)
{
    __shared__ float csh[8];
    const int blk = blockIdx.x;          // 128 blocks: (b,h) x half-e
    const int tid = threadIdx.x;
    const int b = blk >> 4, h = (blk >> 1) & 7;
    const int e = (blk & 1) * 256 + tid;

    if (tid < 8) {
        float s = 0.f;
        #pragma unroll 8
        for (int lcc = 0; lcc < 64; ++lcc)
            s += pbpart[((size_t)b * 64 + lcc) * 64 + h * 8 + tid];
        csh[tid] = s;
    }
    __syncthreads();

    const int i = ((b * 8 + h) << 9) + e;
    float s = 0.f;
    #pragma unroll
    for (int kc = 0; kc < 64; ++kc) s += partial[(size_t)kc * 32768 + i];
    float bt = 0.f;
    #pragma unroll
    for (int g = 0; g < 8; ++g) bt += csh[g] * bv[g * 512 + e];
    out[i] = s + bt;
}

extern "C" void kernel_launch(void* const* d_in, const int* in_sizes, int n_in,
                              void* d_out, int out_size, void* d_ws, size_t ws_size,
                              hipStream_t stream)
{
    const float* queries = (const float*)d_in[0];
    const float* keys    = (const float*)d_in[1];
    const float* values  = (const float*)d_in[2];
    const float* Wq      = (const float*)d_in[3];
    const float* bq      = (const float*)d_in[4];
    const float* Wk      = (const float*)d_in[5];
    const float* bk      = (const float*)d_in[6];
    const float* Wv      = (const float*)d_in[7];
    const float* bv      = (const float*)d_in[8];

    unsigned short* xq  = (unsigned short*)d_ws;
    unsigned short* xk  = xq  + (1u << 21);
    unsigned short* wtq = xk  + (1u << 21);
    unsigned short* wtk = wtq + (1u << 21);
    unsigned char*  Q   = (unsigned char*)(wtk + (1u << 21));
    unsigned char*  Kb  = Q + (1u << 24);
    float* P      = (float*)(Kb + (1u << 24));
    float* pbpart = P + 262144;
    float* ypart  = pbpart + 32768;
    float* part   = ypart + 4 * 262144;

    prep<<<dim3(2048, 1, 4), 256, 0, stream>>>(queries, keys, xq, xk, Wq, Wk, wtq, wtk);
    gemm_bt256<<<dim3(16, 16, 2), 512, 0, stream>>>(xq, xk, wtq, wtk, bq, bk, Q, Kb);
    mfscores<<<dim3(8, 64), 256, 0, stream>>>(Q, Kb, P, pbpart);
    ykern<<<dim3(8, 8, 4), 256, 0, stream>>>(P, values, ypart);
    vgemm<<<dim3(8, 64), 256, 0, stream>>>(ypart, Wv, part);
    finalize<<<dim3(128), 256, 0, stream>>>(part, pbpart, bv, (float*)d_out);
}

// Round 7
// 84.736 us; speedup vs baseline: 1.3111x; 1.1174x over previous
//
#include <hip/hip_runtime.h>

// B=8, L=512, D=512, H=8. Q/K GEMMs: M=4096, N=4096, K=512 (bf16 MFMA, 256^2 8-phase,
// swapped-operand MFMA + LDS-transposed coalesced FP8 epilogue via v_cvt_pk_fp8_f32).
// Q,K stored fp8-e4m3; scores use fp8 MFMA (16x16x32) on (l-parity,h) packed tiles.
// V path (all f32): P' = softmax + 63.875; Y = sum_l P'*Xv; out = Y @ Wv + c*bv.

using bf16x8 = __attribute__((ext_vector_type(8))) short;
using f32x4  = __attribute__((ext_vector_type(4))) float;

__device__ __forceinline__ unsigned short f2bf(float f) {
    union { float f; unsigned int u; } c; c.f = f;
    unsigned int u = c.u;
    u += 0x7FFFu + ((u >> 16) & 1u);   // RTNE
    return (unsigned short)(u >> 16);
}
__device__ __forceinline__ float bflo(unsigned int u) {
    union { unsigned int u; float f; } c; c.u = u << 16; return c.f;
}
__device__ __forceinline__ float bfhi(unsigned int u) {
    union { unsigned int u; float f; } c; c.u = u & 0xFFFF0000u; return c.f;
}

#define GLOAD16(gp, lp) __builtin_amdgcn_global_load_lds( \
    (const __attribute__((address_space(1))) unsigned int*)(gp), \
    (__attribute__((address_space(3))) unsigned int*)(lp), 16, 0, 0)

// ---------------- kernel 1: prep = convert Xq/Xk (z=0,1) + transpose Wq/Wk (z=2,3) ---
__global__ __launch_bounds__(256) void prep(
    const float* __restrict__ x0, const float* __restrict__ x1,
    unsigned short* __restrict__ o0, unsigned short* __restrict__ o1,
    const float* __restrict__ w0, const float* __restrict__ w1,
    unsigned short* __restrict__ t0, unsigned short* __restrict__ t1)
{
    const int z = blockIdx.z;
    if (z < 2) {
        const float* src = (z == 0) ? x0 : x1;
        unsigned short* dst = (z == 0) ? o0 : o1;
        int i = (blockIdx.x * 256 + threadIdx.x) * 4;
        float4 v = *(const float4*)(src + i);
        ushort4 o;
        o.x = f2bf(v.x); o.y = f2bf(v.y); o.z = f2bf(v.z); o.w = f2bf(v.w);
        *(ushort4*)(dst + i) = o;
    } else {
        const float* W = (z == 2) ? w0 : w1;
        unsigned short* T = (z == 2) ? t0 : t1;
        __shared__ float tile[32][33];
        const int n0 = (blockIdx.x & 127) * 32, k0 = (blockIdx.x >> 7) * 32;
        const int tx = threadIdx.x & 31, ty = threadIdx.x >> 5;   // (32, 8)
        #pragma unroll
        for (int j = 0; j < 32; j += 8)
            tile[ty + j][tx] = W[(size_t)(k0 + ty + j) * 4096 + n0 + tx];
        __syncthreads();
        #pragma unroll
        for (int j = 0; j < 32; j += 8)
            T[(size_t)(n0 + ty + j) * 512 + k0 + tx] = f2bf(tile[tx][ty + j]);
    }
}

// ---------------- kernel 2: 256^2 8-phase bf16 GEMM, fp8 coalesced epilogue ----------
__global__ __launch_bounds__(512) void gemm_bt256(
    const unsigned short* __restrict__ a0, const unsigned short* __restrict__ a1,
    const unsigned short* __restrict__ w0, const unsigned short* __restrict__ w1,
    const float* __restrict__ b0, const float* __restrict__ b1,
    unsigned char* __restrict__ c0, unsigned char* __restrict__ c1)
{
    const unsigned short* A;  const unsigned short* Bt; const float* bias; unsigned char* C;
    if (blockIdx.z == 0) { A = a0; Bt = w0; bias = b0; C = c0; }
    else                 { A = a1; Bt = w1; bias = b1; C = c1; }

    __shared__ __align__(16) unsigned short SH[65536];   // 128 KiB: As(2x32KB) | Bs(2x32KB)

    const int tid  = threadIdx.x;
    const int lane = tid & 63;
    const int wid  = tid >> 6;
    const int wr   = wid >> 2;
    const int wn   = wid & 3;
    // XCD-chunked bijective swizzle
    const int linb = blockIdx.y * 16 + blockIdx.x;
    const int swz  = (linb & 7) * 32 + (linb >> 3);
    const int bx   = (swz >> 6) * 4 + (swz & 3);
    const int by   = (swz >> 2) & 15;
    const int row0 = by * 256;
    const int n0   = bx * 256;
    const int sgran = (lane & 7) ^ (lane >> 3);

    // Hoisted ds_read bases. Key: (row & 7) == (lane & 7) for all fragment rows,
    // so the XOR swizzle byte is per-lane constant; every ds_read is base + imm.
    const int swb0 = (((lane >> 4)    ) ^ (lane & 7)) << 4;
    const int swb1 = (((lane >> 4) | 4) ^ (lane & 7)) << 4;
    const char* bA0 = (const char*)SH + (wr * 128 + (lane & 15)) * 128 + swb0;
    const char* bA1 = (const char*)SH + (wr * 128 + (lane & 15)) * 128 + swb1;
    const char* bB0 = (const char*)SH + 65536 + (wn * 64 + (lane & 15)) * 128 + swb0;
    const char* bB1 = (const char*)SH + 65536 + (wn * 64 + (lane & 15)) * 128 + swb1;

#define LD_A(c, m, s) (*(const bf16x8*)(((s) ? bA1 : bA0) + (c) * 32768 + (m) * 2048))
#define LD_B(c, n, s) (*(const bf16x8*)(((s) ? bB1 : bB0) + (c) * 32768 + (n) * 2048))

    // Hoisted per-lane global staging bases (pre-swizzled source granule).
    const unsigned short* gA = A  + (size_t)(row0 + wid * 8 + (lane >> 3)) * 512 + sgran * 8;
    const unsigned short* gB = Bt + (size_t)(n0   + wid * 8 + (lane >> 3)) * 512 + sgran * 8;

    // stage one half-tile: (buf, half) fixed LDS dest, global = base + half/sub + t*64
#define STAGE_A(gp, buf, half, trel)                                              \
    {                                                                             \
        GLOAD16((gp) + ((half) * 128      ) * 512 + (trel) * 64,                  \
                SH + (buf) * 16384 + ((half) * 128      + wid * 8) * 64);         \
        GLOAD16((gp) + ((half) * 128 + 64 ) * 512 + (trel) * 64,                  \
                SH + (buf) * 16384 + ((half) * 128 + 64 + wid * 8) * 64);         \
    }
#define STAGE_B(gp, buf, half, trel)                                              \
    {                                                                             \
        GLOAD16((gp) + ((half) * 128      ) * 512 + (trel) * 64,                  \
                SH + 32768 + (buf) * 16384 + ((half) * 128      + wid * 8) * 64); \
        GLOAD16((gp) + ((half) * 128 + 64 ) * 512 + (trel) * 64,                  \
                SH + 32768 + (buf) * 16384 + ((half) * 128 + 64 + wid * 8) * 64); \
    }

#define BAR() __builtin_amdgcn_s_barrier()
#define VMC4() asm volatile("s_waitcnt vmcnt(4)" ::: "memory")
#define VMC0() asm volatile("s_waitcnt vmcnt(0)" ::: "memory")

    f32x4 acc[8][4];
    #pragma unroll
    for (int m = 0; m < 8; ++m)
        #pragma unroll
        for (int n = 0; n < 4; ++n)
            acc[m][n] = (f32x4){0.f, 0.f, 0.f, 0.f};

    bf16x8 bfr[4][2];
    bf16x8 fa0, fa1, fa2, fa3;

#define LDA_Q(c, q) { fa0 = LD_A(c, 2*(q), 0); fa1 = LD_A(c, 2*(q), 1);           \
                      fa2 = LD_A(c, 2*(q)+1, 0); fa3 = LD_A(c, 2*(q)+1, 1); }
#define LDB_ALL(c) { _Pragma("unroll") for (int n = 0; n < 4; ++n) {              \
                       bfr[n][0] = LD_B(c, n, 0); bfr[n][1] = LD_B(c, n, 1); } }
#define MFMA_Q(q) { __builtin_amdgcn_s_setprio(1);                                \
    _Pragma("unroll") for (int n = 0; n < 4; ++n) {                               \
      acc[2*(q)][n]   = __builtin_amdgcn_mfma_f32_16x16x32_bf16(bfr[n][0], fa0, acc[2*(q)][n],   0,0,0); \
      acc[2*(q)][n]   = __builtin_amdgcn_mfma_f32_16x16x32_bf16(bfr[n][1], fa1, acc[2*(q)][n],   0,0,0); \
      acc[2*(q)+1][n] = __builtin_amdgcn_mfma_f32_16x16x32_bf16(bfr[n][0], fa2, acc[2*(q)+1][n], 0,0,0); \
      acc[2*(q)+1][n] = __builtin_amdgcn_mfma_f32_16x16x32_bf16(bfr[n][1], fa3, acc[2*(q)+1][n], 0,0,0); } \
    __builtin_amdgcn_s_setprio(0); }

    // prologue: buf0.B(t0), buf0.A(t0), buf1.B(t1)
    STAGE_B(gB, 0, 0, 0); STAGE_B(gB, 0, 1, 0);
    STAGE_A(gA, 0, 0, 0); STAGE_A(gA, 0, 1, 0);
    STAGE_B(gB, 1, 0, 1); STAGE_B(gB, 1, 1, 1);
    VMC4();
    BAR();

    const unsigned short* gAt = gA;   // tile 2i base
    const unsigned short* gBt = gB;
    for (int i = 0; i < 4; ++i) {
        const bool s23 = (i < 3);

        LDA_Q(0, 0); LDB_ALL(0);
        STAGE_A(gAt, 1, 0, 1);
        BAR(); MFMA_Q(0); BAR();

        LDA_Q(0, 1);
        STAGE_A(gAt, 1, 1, 1);
        BAR(); MFMA_Q(1); BAR();

        LDA_Q(0, 2);
        if (s23) STAGE_B(gBt, 0, 0, 2);
        BAR(); MFMA_Q(2); BAR();

        LDA_Q(0, 3);
        if (s23) STAGE_B(gBt, 0, 1, 2);
        BAR(); MFMA_Q(3);
        if (s23) { VMC4(); } else { VMC0(); }
        BAR();

        LDA_Q(1, 0); LDB_ALL(1);
        if (s23) STAGE_A(gAt, 0, 0, 2);
        BAR(); MFMA_Q(0); BAR();

        LDA_Q(1, 1);
        if (s23) STAGE_A(gAt, 0, 1, 2);
        BAR(); MFMA_Q(1); BAR();

        LDA_Q(1, 2);
        if (s23) STAGE_B(gBt, 1, 0, 3);
        BAR(); MFMA_Q(2); BAR();

        LDA_Q(1, 3);
        if (s23) STAGE_B(gBt, 1, 1, 3);
        BAR(); MFMA_Q(3);
        if (s23) { VMC4(); }
        BAR();

        gAt += 128; gBt += 128;
    }

    // ---- epilogue: acc -> swizzled fp8 LDS tile (256x256 = 64 KB) -> coalesced C ----
    {
        const int q  = lane >> 4;
        const int tr = wr * 128 + (lane & 15);
        unsigned char* SB = (unsigned char*)SH;
        #pragma unroll
        for (int n = 0; n < 4; ++n) {
            float4 bb = *(const float4*)(bias + n0 + wn * 64 + n * 16 + q * 4);
            const int g16 = wn * 4 + n;               // 16B granule index (16 per 256B row)
            #pragma unroll
            for (int m = 0; m < 8; ++m) {
                const int trm = tr + m * 16;
                unsigned int pk = __builtin_amdgcn_cvt_pk_fp8_f32(
                    acc[m][n][0] + bb.x, acc[m][n][1] + bb.y, 0u, false);
                pk = __builtin_amdgcn_cvt_pk_fp8_f32(
                    acc[m][n][2] + bb.z, acc[m][n][3] + bb.w, pk, true);
                *(unsigned int*)(SB + trm * 256 + ((g16 ^ (trm & 15)) << 4) + q * 4) = pk;
            }
        }
        BAR();
        #pragma unroll
        for (int it = 0; it < 8; ++it) {
            const int f = it * 512 + tid;             // 4096 chunks of 16B
            const int rr = f >> 4, gg = f & 15;
            uint4 v = *(const uint4*)(SB + rr * 256 + ((gg ^ (rr & 15)) << 4));
            *(uint4*)(C + (size_t)(row0 + rr) * 4096 + gg * 16 + n0) = v;
        }
    }
#undef STAGE_A
#undef STAGE_B
#undef LD_A
#undef LD_B
}

// ---------------- kernel 3: fp8-MFMA scores + softmax + pb-partials ------------------
__global__ __launch_bounds__(256) void mfscores(const unsigned char* __restrict__ Q,
                                                const unsigned char* __restrict__ K,
                                                float* __restrict__ P,
                                                float* __restrict__ pbpart)
{
    __shared__ float Pl[8 * 64];
    const int b = blockIdx.x, lc = blockIdx.y;       // (8, 64)
    const int tid = threadIdx.x, lane = tid & 63, w = tid >> 6;
    const int l0 = lc * 8;

    const int colr = lane & 15;                       // A-row / B-col index
    const int ko   = lane >> 4;                       // k-octet within k-tile
    const int la   = l0 + w * 2 + (colr >> 3);        // this row/col's l
    const int hh   = colr & 7;
    const unsigned char* qrow = Q + (size_t)(b * 512 + la) * 4096 + hh * 512 + ko * 8;
    const unsigned char* krow = K + (size_t)(b * 512 + la) * 4096 + hh * 512 + ko * 8;

    f32x4 acc = (f32x4){0.f, 0.f, 0.f, 0.f};
    #pragma unroll
    for (int kt = 0; kt < 16; ++kt) {
        long long av = *(const long long*)(qrow + kt * 32);
        long long bv = *(const long long*)(krow + kt * 32);
        acc = __builtin_amdgcn_mfma_f32_16x16x32_fp8_fp8(av, bv, acc, 0, 0, 0);
    }

    const int lpr = ko >> 1;
    const int lpc = (lane >> 3) & 1;
    #pragma unroll
    for (int r = 0; r < 4; ++r) {
        float s = acc[r] * 0.04419417382415922f;      // 1/sqrt(512)
        float m = s;
        m = fmaxf(m, __shfl_xor(m, 1));
        m = fmaxf(m, __shfl_xor(m, 2));
        m = fmaxf(m, __shfl_xor(m, 4));
        float e = __expf(s - m);
        float ss = e;
        ss += __shfl_xor(ss, 1);
        ss += __shfl_xor(ss, 2);
        ss += __shfl_xor(ss, 4);
        float p = e / ss + 63.875f;                   // fold uniform part
        if (lpr == lpc)
            Pl[(w * 2 + lpr) * 64 + ((ko & 1) * 4 + r) * 8 + (lane & 7)] = p;
    }
    __syncthreads();

    {   // write P (8 x 64) coalesced
        const int l = tid >> 5, off = (tid & 31) * 2;
        float2 v = *(const float2*)&Pl[l * 64 + off];
        *(float2*)(P + (size_t)(b * 512 + l0 + l) * 64 + off) = v;
    }
    if (tid < 64) {
        float s = 0.f;
        #pragma unroll
        for (int l = 0; l < 8; ++l) s += Pl[l * 64 + tid];
        pbpart[((size_t)b * 64 + lc) * 64 + tid] = s;
    }
}

// ---------------- kernel 4: ypart[lc,b,hg,d] = sum_{l in chunk} P' * Xv --------------
__global__ __launch_bounds__(256) void ykern(const float* __restrict__ P,
                                             const float* __restrict__ Xv,
                                             float* __restrict__ ypart)
{
    __shared__ float Pl[128 * 64];
    __shared__ float Xl[128 * 64];
    const int b = blockIdx.x, dt = blockIdx.y, lc = blockIdx.z;
    const int tid = threadIdx.x;
    const int tm = tid & 15, te = tid >> 4;

    const float* Pg = P + ((size_t)b * 512 + lc * 128) * 64;
    #pragma unroll
    for (int i = 0; i < 8; ++i)
        *(float4*)&Pl[(i * 256 + tid) * 4] = *(const float4*)(Pg + (size_t)(i * 256 + tid) * 4);
    const float* Xg = Xv + ((size_t)b * 512 + lc * 128) * 512 + dt * 64;
    #pragma unroll
    for (int i = 0; i < 8; ++i) {
        int flat = i * 256 + tid;
        int r = flat >> 4, q = flat & 15;
        *(float4*)&Xl[r * 64 + q * 4] = *(const float4*)(Xg + (size_t)r * 512 + q * 4);
    }
    __syncthreads();

    float4 acc[4];
    #pragma unroll
    for (int i = 0; i < 4; ++i) acc[i] = make_float4(0.f, 0.f, 0.f, 0.f);

    for (int l = 0; l < 128; ++l) {
        float4 pv = *(const float4*)&Pl[l * 64 + tm * 4];
        float4 xv = *(const float4*)&Xl[l * 64 + te * 4];
        acc[0].x += pv.x * xv.x; acc[0].y += pv.x * xv.y; acc[0].z += pv.x * xv.z; acc[0].w += pv.x * xv.w;
        acc[1].x += pv.y * xv.x; acc[1].y += pv.y * xv.y; acc[1].z += pv.y * xv.z; acc[1].w += pv.y * xv.w;
        acc[2].x += pv.z * xv.x; acc[2].y += pv.z * xv.y; acc[2].z += pv.z * xv.z; acc[2].w += pv.z * xv.w;
        acc[3].x += pv.w * xv.x; acc[3].y += pv.w * xv.y; acc[3].z += pv.w * xv.z; acc[3].w += pv.w * xv.w;
    }
    #pragma unroll
    for (int i = 0; i < 4; ++i)
        *(float4*)&ypart[(((size_t)lc * 8 + b) * 64 + tm * 4 + i) * 512 + dt * 64 + te * 4] = acc[i];
}

// ---------------- kernel 5: split-K vgemm (yreduce fused into A-stage) ---------------
__global__ __launch_bounds__(256) void vgemm(const float* __restrict__ ypart,
                                             const float* __restrict__ Wv,
                                             float* __restrict__ partial)
{
    __shared__ float Al[64 * 64];
    __shared__ float Bl[64 * 64];
    const int et = blockIdx.x, kc = blockIdx.y;
    const int g = kc >> 3, d0 = (kc & 7) * 64, e0 = et * 64;
    const int tid = threadIdx.x;
    const int tm = tid & 15, te = tid >> 4;

    #pragma unroll
    for (int i = 0; i < 4; ++i) {
        int flat = i * 256 + tid;
        int bh = flat >> 4, dq = flat & 15;
        int yrow = (bh >> 3) * 64 + (bh & 7) * 8 + g;
        size_t base = ((size_t)(yrow >> 6) * 64 + (yrow & 63)) * 512 + d0 + dq * 4;
        float4 v = *(const float4*)(ypart + base);
        #pragma unroll
        for (int lc = 1; lc < 4; ++lc) {
            float4 t = *(const float4*)(ypart + (size_t)lc * 262144 + base);
            v.x += t.x; v.y += t.y; v.z += t.z; v.w += t.w;
        }
        *(float4*)&Al[bh * 64 + ((dq ^ (bh >> 2)) << 2)] = v;
    }
    #pragma unroll
    for (int i = 0; i < 4; ++i) {
        int flat = i * 256 + tid;
        int kk = flat >> 4, eq = flat & 15;
        *(float4*)&Bl[kk * 64 + eq * 4] =
            *(const float4*)(Wv + (size_t)(d0 + kk) * 4096 + g * 512 + e0 + eq * 4);
    }
    __syncthreads();

    float4 acc[4];
    #pragma unroll
    for (int j = 0; j < 4; ++j) acc[j] = make_float4(0.f, 0.f, 0.f, 0.f);

    for (int k = 0; k < 64; ++k) {
        float4 b4 = *(const float4*)&Bl[k * 64 + te * 4];
        const int gcol = (((k >> 2) ^ tm) << 2) + (k & 3);
        #pragma unroll
        for (int j = 0; j < 4; ++j) {
            float a = Al[(tm * 4 + j) * 64 + gcol];
            acc[j].x += a * b4.x; acc[j].y += a * b4.y;
            acc[j].z += a * b4.z; acc[j].w += a * b4.w;
        }
    }
    #pragma unroll
    for (int j = 0; j < 4; ++j)
        *(float4*)&partial[(size_t)kc * 32768 + (tm * 4 + j) * 512 + e0 + te * 4] = acc[j];
}

// ---------------- kernel 6: finalize: out = sum_kc partial + sum_g c*bv --------------
__global__ __launch_bounds__(256) void finalize(const float* __restrict__ partial,
                                                const float* __restrict__ pbpart,
                                                const float* __restrict__ bv,
                                                float* __restrict__ out)
{
    __shared__ float csh[8];
    const int blk = blockIdx.x;          // 128 blocks: (b,h) x half-e
    const int tid = threadIdx.x;
    const int b = blk >> 4, h = (blk >> 1) & 7;
    const int e = (blk & 1) * 256 + tid;

    if (tid < 8) {
        float s = 0.f;
        #pragma unroll 8
        for (int lcc = 0; lcc < 64; ++lcc)
            s += pbpart[((size_t)b * 64 + lcc) * 64 + h * 8 + tid];
        csh[tid] = s;
    }
    __syncthreads();

    const int i = ((b * 8 + h) << 9) + e;
    float s = 0.f;
    #pragma unroll
    for (int kc = 0; kc < 64; ++kc) s += partial[(size_t)kc * 32768 + i];
    float bt = 0.f;
    #pragma unroll
    for (int g = 0; g < 8; ++g) bt += csh[g] * bv[g * 512 + e];
    out[i] = s + bt;
}

extern "C" void kernel_launch(void* const* d_in, const int* in_sizes, int n_in,
                              void* d_out, int out_size, void* d_ws, size_t ws_size,
                              hipStream_t stream)
{
    const float* queries = (const float*)d_in[0];
    const float* keys    = (const float*)d_in[1];
    const float* values  = (const float*)d_in[2];
    const float* Wq      = (const float*)d_in[3];
    const float* bq      = (const float*)d_in[4];
    const float* Wk      = (const float*)d_in[5];
    const float* bk      = (const float*)d_in[6];
    const float* Wv      = (const float*)d_in[7];
    const float* bv      = (const float*)d_in[8];

    unsigned short* xq  = (unsigned short*)d_ws;
    unsigned short* xk  = xq  + (1u << 21);
    unsigned short* wtq = xk  + (1u << 21);
    unsigned short* wtk = wtq + (1u << 21);
    unsigned char*  Q   = (unsigned char*)(wtk + (1u << 21));
    unsigned char*  Kb  = Q + (1u << 24);
    float* P      = (float*)(Kb + (1u << 24));
    float* pbpart = P + 262144;
    float* ypart  = pbpart + 32768;
    float* part   = ypart + 4 * 262144;

    prep<<<dim3(2048, 1, 4), 256, 0, stream>>>(queries, keys, xq, xk, Wq, Wk, wtq, wtk);
    gemm_bt256<<<dim3(16, 16, 2), 512, 0, stream>>>(xq, xk, wtq, wtk, bq, bk, Q, Kb);
    mfscores<<<dim3(8, 64), 256, 0, stream>>>(Q, Kb, P, pbpart);
    ykern<<<dim3(8, 8, 4), 256, 0, stream>>>(P, values, ypart);
    vgemm<<<dim3(8, 64), 256, 0, stream>>>(ypart, Wv, part);
    finalize<<<dim3(128), 256, 0, stream>>>(part, pbpart, bv, (float*)d_out);
}